// Round 4
// baseline (1714.602 us; speedup 1.0000x reference)
//
#include <hip/hip_runtime.h>
#include <hip/hip_bf16.h>
#include <cstdint>
#include <cstddef>

// GCNEncoder: two-branch GCN on MI355X.
// Round 4: conv1 aggregation made L2-resident via column-chunked h/xl layout
// ([16 chunks][50000 nodes][32 cols] bf16; chunk = XCD via blockIdx&7 round-robin).
// Pipeline:
//   1) memset zero-region (deg/cursor/cnt/c_l/c_g)
//   2) cvt x -> bf16 xb[50048][2112], W -> bf16 transposed Wt[512][2112]
//   3) degree / dinv / scan -> CSR / scatter / graph counts / c-matrix build
//   4) GEMM1 (MFMA): hch[16][50000][32]bf16 = xb @ Wt^T (chunk-major C-write)
//   5) k_aggc x2: CSR pull per (node, 32-col chunk); gathers hit per-XCD L2
//   6) k_pool2: Spart = c^T @ xl chunks (sequential); k_pool_reduce -> S
//   7) final: (S@W2)/cnt + b2, concat, @W_fuse + b_fuse, relu -> out[64x128] fp32

#define N_NODES 50000
#define N_GRAPHS 64
#define IN_DIM 2063
#define HIDDEN 256
#define OUT_DIM 128
#define EDGES_L 800000
#define EDGES_G 1600000
#define HCOLS 512   // [local 0..255 | global 256..511]
#define KPAD 2112   // 33 * 64
#define MPAD 50048  // 391 * 128
#define PCH 256                                  // nodes per pool2 chunk
#define NCHUNK ((N_NODES + PCH - 1) / PCH)       // 196

typedef __attribute__((ext_vector_type(8))) __bf16 bf16x8;
typedef __attribute__((ext_vector_type(4))) float f32x4;

__device__ __forceinline__ float bf2f(unsigned short u) {
  union { unsigned int i; float f; } c; c.i = ((unsigned int)u) << 16; return c.f;
}
__device__ __forceinline__ unsigned short f2bf(float f) {
  __hip_bfloat16 h = __float2bfloat16(f);
  return *reinterpret_cast<unsigned short*>(&h);
}

// ---------------------------------------------------------------- converts
__global__ void k_cvt_x(const float* __restrict__ x, unsigned short* __restrict__ xb) {
  const int G = KPAD / 4;  // 528 groups of 4 per row
  long long i = (long long)blockIdx.x * blockDim.x + threadIdx.x;
  if (i >= (long long)MPAD * G) return;
  int row = (int)(i / G);
  int k = (int)(i - (long long)row * G) * 4;
  ushort4 o;
  float v0 = 0.f, v1 = 0.f, v2 = 0.f, v3 = 0.f;
  if (row < N_NODES) {
    const float* xr = x + (size_t)row * IN_DIM;
    if (k + 0 < IN_DIM) v0 = xr[k + 0];
    if (k + 1 < IN_DIM) v1 = xr[k + 1];
    if (k + 2 < IN_DIM) v2 = xr[k + 2];
    if (k + 3 < IN_DIM) v3 = xr[k + 3];
  }
  o.x = f2bf(v0); o.y = f2bf(v1); o.z = f2bf(v2); o.w = f2bf(v3);
  *(ushort4*)(xb + (size_t)row * KPAD + k) = o;
}

__global__ void k_cvt_w(const float* __restrict__ Wl, const float* __restrict__ Wg,
                        unsigned short* __restrict__ Wt) {
  int i = blockIdx.x * blockDim.x + threadIdx.x;
  if (i >= HCOLS * KPAD) return;
  int n = i / KPAD;
  int k = i - n * KPAD;
  float v = 0.f;
  if (k < IN_DIM) {
    v = (n < HIDDEN) ? Wl[(size_t)k * HIDDEN + n] : Wg[(size_t)k * HIDDEN + (n - HIDDEN)];
  }
  Wt[(size_t)n * KPAD + k] = f2bf(v);
}

// ---------------------------------------------------------------- small kernels
__global__ void k_degree(const int* __restrict__ dst, int E, int* __restrict__ deg) {
  int e = blockIdx.x * blockDim.x + threadIdx.x;
  if (e < E) atomicAdd(&deg[dst[e]], 1);
}

__global__ void k_dinv(const int* __restrict__ degL, const int* __restrict__ degG,
                       float* __restrict__ dinvL, float* __restrict__ dinvG) {
  int i = blockIdx.x * blockDim.x + threadIdx.x;
  if (i < N_NODES) {
    dinvL[i] = 1.0f / sqrtf((float)(degL[i] + 1));
    dinvG[i] = 1.0f / sqrtf((float)(degG[i] + 1));
  }
}

__global__ void k_scan_block(const int* __restrict__ cnts, int n,
                             int* __restrict__ incl, int* __restrict__ bsums) {
  __shared__ int s[1024];
  int t = threadIdx.x;
  int i = blockIdx.x * 1024 + t;
  int v = (i < n) ? cnts[i] : 0;
  s[t] = v;
  __syncthreads();
  for (int off = 1; off < 1024; off <<= 1) {
    int x = (t >= off) ? s[t - off] : 0;
    __syncthreads();
    s[t] += x;
    __syncthreads();
  }
  if (i < n) incl[i] = s[t];
  if (t == 1023) bsums[blockIdx.x] = s[1023];
}

__global__ void k_scan_tops(int* __restrict__ bsums, int nb) {
  __shared__ int s[64];
  int t = threadIdx.x;
  if (t < nb) s[t] = bsums[t];
  __syncthreads();
  if (t == 0) {
    int run = 0;
    for (int b = 0; b < nb; b++) { int v = s[b]; s[b] = run; run += v; }
  }
  __syncthreads();
  if (t < nb) bsums[t] = s[t];
}

__global__ void k_scan_fix(const int* __restrict__ incl, const int* __restrict__ boffs,
                           int n, int* __restrict__ row_ptr) {
  int i = blockIdx.x * blockDim.x + threadIdx.x;
  if (i < n) row_ptr[i + 1] = incl[i] + boffs[i >> 10];
  if (i == 0) row_ptr[0] = 0;
}

__global__ void k_scatter(const int* __restrict__ src, const int* __restrict__ dst, int E,
                          const float* __restrict__ dinv, const int* __restrict__ row_ptr,
                          int* __restrict__ cursor, int* __restrict__ s_src,
                          float* __restrict__ s_nrm) {
  int e = blockIdx.x * blockDim.x + threadIdx.x;
  if (e < E) {
    int d = dst[e], s = src[e];
    int pos = row_ptr[d] + atomicAdd(&cursor[d], 1);
    s_src[pos] = s;
    s_nrm[pos] = dinv[s] * dinv[d];
  }
}

__global__ void k_count(const int* __restrict__ batch, int* __restrict__ cnt) {
  int i = blockIdx.x * blockDim.x + threadIdx.x;
  if (i < N_NODES) atomicAdd(&cnt[batch[i]], 1);
}

// c[s][g] += norm_e for each edge s->dst in graph g  (low-contention scatter)
__global__ void k_cbuild(const int* __restrict__ src, const int* __restrict__ dst, int E,
                         const float* __restrict__ dinv, const int* __restrict__ batch,
                         float* __restrict__ c) {
  int e = blockIdx.x * blockDim.x + threadIdx.x;
  if (e < E) {
    int s = src[e], d = dst[e];
    atomicAdd(&c[(size_t)s * 64 + batch[d]], dinv[s] * dinv[d]);
  }
}

__global__ void k_cself(const int* __restrict__ batch, const float* __restrict__ dinvL,
                        const float* __restrict__ dinvG, float* __restrict__ cL,
                        float* __restrict__ cG) {
  int i = blockIdx.x * blockDim.x + threadIdx.x;
  if (i < N_NODES) {
    int g = batch[i];
    atomicAdd(&cL[(size_t)i * 64 + g], dinvL[i] * dinvL[i]);
    atomicAdd(&cG[(size_t)i * 64 + g], dinvG[i] * dinvG[i]);
  }
}

// ---------------------------------------------------------------- GEMM1 (bf16 MFMA)
// hch[(col>>5)][row][col&31] = (xb @ Wt^T)[row][col], bf16
__launch_bounds__(256)
__global__ void k_mfma_gemm(const unsigned short* __restrict__ Xb,
                            const unsigned short* __restrict__ Wt,
                            unsigned short* __restrict__ Hch) {
  __shared__ __align__(16) char lds[32768];
  const int tid = threadIdx.x;
  const int lane = tid & 63;
  const int wave = tid >> 6;
  const int wr = wave >> 1, wc = wave & 1;
  const int brow = blockIdx.y * 128;
  const int bcol = blockIdx.x * 128;

  f32x4 acc[4][4];
  const f32x4 zero = {0.f, 0.f, 0.f, 0.f};
#pragma unroll
  for (int m = 0; m < 4; m++)
#pragma unroll
    for (int n = 0; n < 4; n++) acc[m][n] = zero;

  int rowA[4], kcS[4], ldsOff[4];
#pragma unroll
  for (int i = 0; i < 4; i++) {
    int s = (i * 4 + wave) * 64 + lane;
    int row = s >> 3;
    int c = s & 7;
    rowA[i] = row;
    kcS[i] = (c ^ (row & 7)) * 8;
    ldsOff[i] = ((i * 4 + wave) * 64) * 16;
  }

  const int fr = lane & 15;
  const int fq = lane >> 4;
  const int arow0 = wr * 64 + fr;
  const int brow0 = wc * 64 + fr;
  const int sw = lane & 7;

  for (int t = 0; t < KPAD / 64; ++t) {
    const int k0 = t * 64;
#pragma unroll
    for (int i = 0; i < 4; i++) {
      const unsigned short* g = Xb + (size_t)(brow + rowA[i]) * KPAD + k0 + kcS[i];
      __builtin_amdgcn_global_load_lds(
          (const __attribute__((address_space(1))) void*)g,
          (__attribute__((address_space(3))) void*)(lds + ldsOff[i]), 16, 0, 0);
    }
#pragma unroll
    for (int i = 0; i < 4; i++) {
      const unsigned short* g = Wt + (size_t)(bcol + rowA[i]) * KPAD + k0 + kcS[i];
      __builtin_amdgcn_global_load_lds(
          (const __attribute__((address_space(1))) void*)g,
          (__attribute__((address_space(3))) void*)(lds + 16384 + ldsOff[i]), 16, 0, 0);
    }
    __syncthreads();

#pragma unroll
    for (int kk = 0; kk < 2; kk++) {
      const int cidx = ((kk * 4 + fq) ^ sw) * 16;
      bf16x8 av[4], bv[4];
#pragma unroll
      for (int m = 0; m < 4; m++)
        av[m] = *(const bf16x8*)(lds + (arow0 + m * 16) * 128 + cidx);
#pragma unroll
      for (int n = 0; n < 4; n++)
        bv[n] = *(const bf16x8*)(lds + 16384 + (brow0 + n * 16) * 128 + cidx);
#pragma unroll
      for (int m = 0; m < 4; m++)
#pragma unroll
        for (int n = 0; n < 4; n++)
          acc[m][n] = __builtin_amdgcn_mfma_f32_16x16x32_bf16(av[m], bv[n], acc[m][n], 0, 0, 0);
    }
    __syncthreads();
  }

#pragma unroll
  for (int m = 0; m < 4; m++) {
    const int r0 = brow + wr * 64 + m * 16 + fq * 4;
#pragma unroll
    for (int n = 0; n < 4; n++) {
      const int col = bcol + wc * 64 + n * 16 + fr;
      const size_t cb = ((size_t)(col >> 5) * N_NODES) * 32 + (col & 31);
#pragma unroll
      for (int j = 0; j < 4; j++) {
        int r = r0 + j;
        if (r < N_NODES) Hch[cb + (size_t)r * 32] = f2bf(acc[m][n][j]);
      }
    }
  }
}

// --------------------------- conv1 aggregation, column-chunked (L2-resident gather)
// grid.x = 12500 * 8; chunk = blockIdx&7 (+cbase) pins to one XCD's L2 (3.2MB set).
// Block = 4 waves = 4 nodes. Wave: 4 edge-groups x 16 lanes x 2 cols (ushort2).
__global__ void k_aggc(const unsigned short* __restrict__ hch, int cbase,
                       const float* __restrict__ dinv, const int* __restrict__ row_ptr,
                       const int* __restrict__ srcs, const float* __restrict__ norms,
                       const float* __restrict__ bias, unsigned short* __restrict__ xlch) {
  const int chunk = (blockIdx.x & 7) + cbase;
  const int node = (blockIdx.x >> 3) * 4 + (threadIdx.x >> 6);
  const int lane = threadIdx.x & 63;
  const int grp = lane >> 4;
  const int l = lane & 15;
  if (node >= N_NODES) return;
  const unsigned short* __restrict__ hc = hch + (size_t)chunk * N_NODES * 32;
  float a0 = 0.f, a1 = 0.f;
  if (grp == 0) {
    float di = dinv[node];
    float w0 = di * di;  // self-loop norm
    ushort2 u = *(const ushort2*)(hc + (size_t)node * 32 + l * 2);
    a0 = w0 * bf2f(u.x);
    a1 = w0 * bf2f(u.y);
  }
  const int e1 = row_ptr[node + 1];
  for (int e = row_ptr[node] + grp; e < e1; e += 4) {
    int s = srcs[e];
    float w = norms[e];
    ushort2 v = *(const ushort2*)(hc + (size_t)s * 32 + l * 2);
    a0 = fmaf(w, bf2f(v.x), a0);
    a1 = fmaf(w, bf2f(v.y), a1);
  }
  a0 += __shfl_xor(a0, 16); a0 += __shfl_xor(a0, 32);
  a1 += __shfl_xor(a1, 16); a1 += __shfl_xor(a1, 32);
  if (grp == 0) {
    float2 b = *(const float2*)(bias + (chunk - cbase) * 32 + l * 2);
    ushort2 o;
    o.x = f2bf(fmaxf(a0 + b.x, 0.f));
    o.y = f2bf(fmaxf(a1 + b.y, 0.f));
    *(ushort2*)(xlch + ((size_t)chunk * N_NODES + node) * 32 + l * 2) = o;
  }
}

// --------------------------------- pool2: Spart[br][chunk][g][col] = c^T @ xl chunk
__launch_bounds__(256)
__global__ void k_pool2(const unsigned short* __restrict__ xlch,
                        const float* __restrict__ cL, const float* __restrict__ cG,
                        float* __restrict__ Spart) {
  __shared__ float cs[64][64];  // 16 KB: 64 nodes x 64 graphs
  const int t = threadIdx.x;    // col 0..255 (within branch)
  const int chunk = blockIdx.x;
  const int br = blockIdx.y;
  const float* __restrict__ C = br ? cG : cL;
  const size_t xbase = ((size_t)(br * 8 + (t >> 5)) * N_NODES) * 32 + (t & 31);
  const int n0 = chunk * PCH;
  float acc[64];
#pragma unroll
  for (int g = 0; g < 64; g++) acc[g] = 0.f;

  for (int tile = 0; tile < PCH; tile += 64) {
    const int base = n0 + tile;
    __syncthreads();
#pragma unroll
    for (int i = 0; i < 16; i++) {
      int idx = i * 256 + t;  // 0..4095
      int nn = idx >> 6, gg = idx & 63;
      int node = base + nn;
      cs[nn][gg] = (node < N_NODES) ? C[(size_t)node * 64 + gg] : 0.f;
    }
    __syncthreads();
    for (int nn = 0; nn < 64; nn++) {
      int node = base + nn;
      float v = (node < N_NODES) ? bf2f(xlch[xbase + (size_t)node * 32]) : 0.f;
#pragma unroll
      for (int g4 = 0; g4 < 16; g4++) {
        float4 cv = *(const float4*)&cs[nn][g4 * 4];
        acc[g4 * 4 + 0] = fmaf(cv.x, v, acc[g4 * 4 + 0]);
        acc[g4 * 4 + 1] = fmaf(cv.y, v, acc[g4 * 4 + 1]);
        acc[g4 * 4 + 2] = fmaf(cv.z, v, acc[g4 * 4 + 2]);
        acc[g4 * 4 + 3] = fmaf(cv.w, v, acc[g4 * 4 + 3]);
      }
    }
  }
  float* sp = Spart + ((size_t)br * NCHUNK + chunk) * 16384 + t;
#pragma unroll
  for (int g = 0; g < 64; g++) sp[g * 256] = acc[g];
}

__global__ void k_pool_reduce(const float* __restrict__ Spart, float* __restrict__ S) {
  int i = blockIdx.x * blockDim.x + threadIdx.x;  // 0..32767
  if (i >= 2 * 16384) return;
  int br = i >> 14, idx = i & 16383;
  const float* p = Spart + (size_t)br * NCHUNK * 16384 + idx;
  float s = 0.f;
  for (int ch = 0; ch < NCHUNK; ch++) s += p[(size_t)ch * 16384];
  S[i] = s;
}

// ---------------------------------------------------------------- final fuse
__global__ void k_final(const float* __restrict__ S,  // [2][64][256]
                        const float* __restrict__ Wl2, const float* __restrict__ bl2,
                        const float* __restrict__ Wg2, const float* __restrict__ bg2,
                        const float* __restrict__ Wf, const float* __restrict__ bf,
                        const int* __restrict__ cnt, float* __restrict__ out) {
  __shared__ float pl[OUT_DIM], pg[OUT_DIM];
  int g = blockIdx.x, t = threadIdx.x;
  float invc = 1.0f / fmaxf((float)cnt[g], 1.0f);
  const float* Sl = S + (size_t)g * HIDDEN;
  const float* Sg = S + (size_t)N_GRAPHS * HIDDEN + (size_t)g * HIDDEN;
  float al = 0.f, ag = 0.f;
  for (int k = 0; k < HIDDEN; k++) {
    al = fmaf(Sl[k], Wl2[k * OUT_DIM + t], al);
    ag = fmaf(Sg[k], Wg2[k * OUT_DIM + t], ag);
  }
  pl[t] = al * invc + bl2[t];
  pg[t] = ag * invc + bg2[t];
  __syncthreads();
  float o = bf[t];
  for (int j = 0; j < OUT_DIM; j++) {
    o = fmaf(pl[j], Wf[j * OUT_DIM + t], o);
    o = fmaf(pg[j], Wf[(OUT_DIM + j) * OUT_DIM + t], o);
  }
  out[(size_t)g * OUT_DIM + t] = fmaxf(o, 0.f);
}

// ---------------------------------------------------------------- launch
extern "C" void kernel_launch(void* const* d_in, const int* in_sizes, int n_in,
                              void* d_out, int out_size, void* d_ws, size_t ws_size,
                              hipStream_t stream) {
  const float* x = (const float*)d_in[0];
  const int* el = (const int*)d_in[1];
  const int* eg = (const int*)d_in[2];
  const int* batch = (const int*)d_in[3];
  const float* Wl1 = (const float*)d_in[4];
  const float* bl1 = (const float*)d_in[5];
  const float* Wl2 = (const float*)d_in[6];
  const float* bl2 = (const float*)d_in[7];
  const float* Wg1 = (const float*)d_in[8];
  const float* bg1 = (const float*)d_in[9];
  const float* Wg2 = (const float*)d_in[10];
  const float* bg2 = (const float*)d_in[11];
  const float* Wf = (const float*)d_in[12];
  const float* bf = (const float*)d_in[13];
  float* out = (float*)d_out;
  char* ws = (char*)d_ws;

  // ---- workspace layout (256B aligned). Zero-region first (single memset).
  const size_t NPAD = 200192;  // 50000*4 padded
  size_t off = 0;
  int* deg_l = (int*)(ws + off); off += NPAD;
  int* deg_g = (int*)(ws + off); off += NPAD;
  int* cur_l = (int*)(ws + off); off += NPAD;
  int* cur_g = (int*)(ws + off); off += NPAD;
  int* cnt = (int*)(ws + off); off += 256;
  float* c_l = (float*)(ws + off); off += (size_t)N_NODES * 64 * 4;  // 12.8 MB
  float* c_g = (float*)(ws + off); off += (size_t)N_NODES * 64 * 4;  // 12.8 MB
  const size_t zero_bytes = off;
  float* S = (float*)(ws + off); off += (size_t)2 * N_GRAPHS * HIDDEN * 4;
  float* dinv_l = (float*)(ws + off); off += NPAD;
  float* dinv_g = (float*)(ws + off); off += NPAD;
  int* row_l = (int*)(ws + off); off += NPAD;
  int* row_g = (int*)(ws + off); off += NPAD;
  int* incl = (int*)(ws + off); off += NPAD;
  int* bsums = (int*)(ws + off); off += 256;
  int* srcs_l = (int*)(ws + off); off += (size_t)EDGES_L * 4;
  float* norm_l = (float*)(ws + off); off += (size_t)EDGES_L * 4;
  int* srcs_g = (int*)(ws + off); off += (size_t)EDGES_G * 4;
  float* norm_g = (float*)(ws + off); off += (size_t)EDGES_G * 4;
  unsigned short* xb = (unsigned short*)(ws + off); off += (size_t)MPAD * KPAD * 2;  // 211 MB
  unsigned short* Wt = (unsigned short*)(ws + off); off += (size_t)HCOLS * KPAD * 2;
  unsigned short* hch = (unsigned short*)(ws + off); off += (size_t)16 * N_NODES * 32 * 2;  // 51.2 MB
  unsigned short* xlch = (unsigned short*)(ws + off); off += (size_t)16 * N_NODES * 32 * 2; // 51.2 MB
  // Spart aliases xb: xb is dead after k_mfma_gemm, Spart written after (pool2).
  float* Spart = (float*)xb;  // 2*196*16384*4 = 25.7 MB << 211 MB

  const int* srcL = el;
  const int* dstL = el + EDGES_L;
  const int* srcG = eg;
  const int* dstG = eg + EDGES_G;

  hipMemsetAsync(ws, 0, zero_bytes, stream);

  {
    long long tot = (long long)MPAD * (KPAD / 4);
    k_cvt_x<<<(int)((tot + 255) / 256), 256, 0, stream>>>(x, xb);
    k_cvt_w<<<(HCOLS * KPAD + 255) / 256, 256, 0, stream>>>(Wl1, Wg1, Wt);
  }

  k_degree<<<(EDGES_L + 255) / 256, 256, 0, stream>>>(dstL, EDGES_L, deg_l);
  k_degree<<<(EDGES_G + 255) / 256, 256, 0, stream>>>(dstG, EDGES_G, deg_g);
  k_dinv<<<(N_NODES + 255) / 256, 256, 0, stream>>>(deg_l, deg_g, dinv_l, dinv_g);

  const int NB = (N_NODES + 1023) / 1024;  // 49
  k_scan_block<<<NB, 1024, 0, stream>>>(deg_l, N_NODES, incl, bsums);
  k_scan_tops<<<1, 64, 0, stream>>>(bsums, NB);
  k_scan_fix<<<(N_NODES + 255) / 256, 256, 0, stream>>>(incl, bsums, N_NODES, row_l);
  k_scan_block<<<NB, 1024, 0, stream>>>(deg_g, N_NODES, incl, bsums);
  k_scan_tops<<<1, 64, 0, stream>>>(bsums, NB);
  k_scan_fix<<<(N_NODES + 255) / 256, 256, 0, stream>>>(incl, bsums, N_NODES, row_g);

  k_scatter<<<(EDGES_L + 255) / 256, 256, 0, stream>>>(srcL, dstL, EDGES_L, dinv_l, row_l,
                                                       cur_l, srcs_l, norm_l);
  k_scatter<<<(EDGES_G + 255) / 256, 256, 0, stream>>>(srcG, dstG, EDGES_G, dinv_g, row_g,
                                                       cur_g, srcs_g, norm_g);
  k_count<<<(N_NODES + 255) / 256, 256, 0, stream>>>(batch, cnt);

  // c-matrix build (needs dinv only)
  k_cbuild<<<(EDGES_L + 255) / 256, 256, 0, stream>>>(srcL, dstL, EDGES_L, dinv_l, batch, c_l);
  k_cbuild<<<(EDGES_G + 255) / 256, 256, 0, stream>>>(srcG, dstG, EDGES_G, dinv_g, batch, c_g);
  k_cself<<<(N_NODES + 255) / 256, 256, 0, stream>>>(batch, dinv_l, dinv_g, c_l, c_g);

  // GEMM1: 4 N-tiles x 391 M-tiles (chunk-major C-write)
  dim3 ggrid(4, MPAD / 128);
  k_mfma_gemm<<<ggrid, 256, 0, stream>>>(xb, Wt, hch);

  // conv1 aggregation: 12500 node-groups x 8 chunks; chunk pinned to XCD via blockIdx&7
  const int aggGrid = (N_NODES / 4) * 8;  // 100000
  k_aggc<<<aggGrid, 256, 0, stream>>>(hch, 0, dinv_l, row_l, srcs_l, norm_l, bl1, xlch);
  k_aggc<<<aggGrid, 256, 0, stream>>>(hch, 8, dinv_g, row_g, srcs_g, norm_g, bg1, xlch);

  // pool2 (reads xl + c sequentially; writes partials; aliased over dead xb)
  dim3 pgrid(NCHUNK, 2);
  k_pool2<<<pgrid, 256, 0, stream>>>(xlch, c_l, c_g, Spart);
  k_pool_reduce<<<(2 * 16384 + 255) / 256, 256, 0, stream>>>(Spart, S);

  k_final<<<N_GRAPHS, OUT_DIM, 0, stream>>>(S, Wl2, bl2, Wg2, bg2, Wf, bf, cnt, out);
}

// Round 5
// 1295.727 us; speedup vs baseline: 1.3233x; 1.3233x over previous
//
#include <hip/hip_runtime.h>
#include <hip/hip_bf16.h>
#include <cstdint>
#include <cstddef>

// GCNEncoder: two-branch GCN on MI355X.
// Round 5: revert to row-major h/xl (round-3 layout); aggregation rewritten for
// MLP: unroll-4 edge loop, fused (src,norm) int2 records, both branches in one
// launch (grid.y=2). Round-4's L2-chunking was latency-bound, not BW-bound.
// Pipeline:
//   1) memset zero-region (deg/cursor/cnt/c_l/c_g)
//   2) cvt x -> bf16 xb[50048][2112], W -> bf16 transposed Wt[512][2112]
//   3) degree / dinv / scan -> CSR / scatter(int2 records) / counts / c-matrix
//   4) GEMM1 (MFMA): h[50000x512]bf16 = xb @ Wt^T
//   5) k_agg (grid.y=2): CSR pull, wave/node, 4-deep unrolled gather, bias+relu
//   6) k_pool2: Spart = c^T @ xl (sequential reads); k_pool_reduce -> S
//   7) final: (S@W2)/cnt + b2, concat, @W_fuse + b_fuse, relu -> out[64x128] fp32

#define N_NODES 50000
#define N_GRAPHS 64
#define IN_DIM 2063
#define HIDDEN 256
#define OUT_DIM 128
#define EDGES_L 800000
#define EDGES_G 1600000
#define HCOLS 512   // [local 0..255 | global 256..511]
#define KPAD 2112   // 33 * 64
#define MPAD 50048  // 391 * 128
#define PCH 256                                  // nodes per pool2 chunk
#define NCHUNK ((N_NODES + PCH - 1) / PCH)       // 196

typedef __attribute__((ext_vector_type(8))) __bf16 bf16x8;
typedef __attribute__((ext_vector_type(4))) float f32x4;

__device__ __forceinline__ float bf2f(unsigned short u) {
  union { unsigned int i; float f; } c; c.i = ((unsigned int)u) << 16; return c.f;
}
__device__ __forceinline__ unsigned short f2bf(float f) {
  __hip_bfloat16 h = __float2bfloat16(f);
  return *reinterpret_cast<unsigned short*>(&h);
}

// ---------------------------------------------------------------- converts
__global__ void k_cvt_x(const float* __restrict__ x, unsigned short* __restrict__ xb) {
  const int G = KPAD / 4;  // 528 groups of 4 per row
  long long i = (long long)blockIdx.x * blockDim.x + threadIdx.x;
  if (i >= (long long)MPAD * G) return;
  int row = (int)(i / G);
  int k = (int)(i - (long long)row * G) * 4;
  ushort4 o;
  float v0 = 0.f, v1 = 0.f, v2 = 0.f, v3 = 0.f;
  if (row < N_NODES) {
    const float* xr = x + (size_t)row * IN_DIM;
    if (k + 0 < IN_DIM) v0 = xr[k + 0];
    if (k + 1 < IN_DIM) v1 = xr[k + 1];
    if (k + 2 < IN_DIM) v2 = xr[k + 2];
    if (k + 3 < IN_DIM) v3 = xr[k + 3];
  }
  o.x = f2bf(v0); o.y = f2bf(v1); o.z = f2bf(v2); o.w = f2bf(v3);
  *(ushort4*)(xb + (size_t)row * KPAD + k) = o;
}

__global__ void k_cvt_w(const float* __restrict__ Wl, const float* __restrict__ Wg,
                        unsigned short* __restrict__ Wt) {
  int i = blockIdx.x * blockDim.x + threadIdx.x;
  if (i >= HCOLS * KPAD) return;
  int n = i / KPAD;
  int k = i - n * KPAD;
  float v = 0.f;
  if (k < IN_DIM) {
    v = (n < HIDDEN) ? Wl[(size_t)k * HIDDEN + n] : Wg[(size_t)k * HIDDEN + (n - HIDDEN)];
  }
  Wt[(size_t)n * KPAD + k] = f2bf(v);
}

// ---------------------------------------------------------------- small kernels
__global__ void k_degree(const int* __restrict__ dst, int E, int* __restrict__ deg) {
  int e = blockIdx.x * blockDim.x + threadIdx.x;
  if (e < E) atomicAdd(&deg[dst[e]], 1);
}

__global__ void k_dinv(const int* __restrict__ degL, const int* __restrict__ degG,
                       float* __restrict__ dinvL, float* __restrict__ dinvG) {
  int i = blockIdx.x * blockDim.x + threadIdx.x;
  if (i < N_NODES) {
    dinvL[i] = 1.0f / sqrtf((float)(degL[i] + 1));
    dinvG[i] = 1.0f / sqrtf((float)(degG[i] + 1));
  }
}

__global__ void k_scan_block(const int* __restrict__ cnts, int n,
                             int* __restrict__ incl, int* __restrict__ bsums) {
  __shared__ int s[1024];
  int t = threadIdx.x;
  int i = blockIdx.x * 1024 + t;
  int v = (i < n) ? cnts[i] : 0;
  s[t] = v;
  __syncthreads();
  for (int off = 1; off < 1024; off <<= 1) {
    int x = (t >= off) ? s[t - off] : 0;
    __syncthreads();
    s[t] += x;
    __syncthreads();
  }
  if (i < n) incl[i] = s[t];
  if (t == 1023) bsums[blockIdx.x] = s[1023];
}

__global__ void k_scan_tops(int* __restrict__ bsums, int nb) {
  __shared__ int s[64];
  int t = threadIdx.x;
  if (t < nb) s[t] = bsums[t];
  __syncthreads();
  if (t == 0) {
    int run = 0;
    for (int b = 0; b < nb; b++) { int v = s[b]; s[b] = run; run += v; }
  }
  __syncthreads();
  if (t < nb) bsums[t] = s[t];
}

__global__ void k_scan_fix(const int* __restrict__ incl, const int* __restrict__ boffs,
                           int n, int* __restrict__ row_ptr) {
  int i = blockIdx.x * blockDim.x + threadIdx.x;
  if (i < n) row_ptr[i + 1] = incl[i] + boffs[i >> 10];
  if (i == 0) row_ptr[0] = 0;
}

// counting-sort edges into CSR slots; record = (src, norm) packed as int2
__global__ void k_scatter(const int* __restrict__ src, const int* __restrict__ dst, int E,
                          const float* __restrict__ dinv, const int* __restrict__ row_ptr,
                          int* __restrict__ cursor, int2* __restrict__ er) {
  int e = blockIdx.x * blockDim.x + threadIdx.x;
  if (e < E) {
    int d = dst[e], s = src[e];
    int pos = row_ptr[d] + atomicAdd(&cursor[d], 1);
    er[pos] = make_int2(s, __float_as_int(dinv[s] * dinv[d]));
  }
}

__global__ void k_count(const int* __restrict__ batch, int* __restrict__ cnt) {
  int i = blockIdx.x * blockDim.x + threadIdx.x;
  if (i < N_NODES) atomicAdd(&cnt[batch[i]], 1);
}

// c[s][g] += norm_e for each edge s->dst in graph g  (low-contention scatter)
__global__ void k_cbuild(const int* __restrict__ src, const int* __restrict__ dst, int E,
                         const float* __restrict__ dinv, const int* __restrict__ batch,
                         float* __restrict__ c) {
  int e = blockIdx.x * blockDim.x + threadIdx.x;
  if (e < E) {
    int s = src[e], d = dst[e];
    atomicAdd(&c[(size_t)s * 64 + batch[d]], dinv[s] * dinv[d]);
  }
}

__global__ void k_cself(const int* __restrict__ batch, const float* __restrict__ dinvL,
                        const float* __restrict__ dinvG, float* __restrict__ cL,
                        float* __restrict__ cG) {
  int i = blockIdx.x * blockDim.x + threadIdx.x;
  if (i < N_NODES) {
    int g = batch[i];
    atomicAdd(&cL[(size_t)i * 64 + g], dinvL[i] * dinvL[i]);
    atomicAdd(&cG[(size_t)i * 64 + g], dinvG[i] * dinvG[i]);
  }
}

// ---------------------------------------------------------------- GEMM1 (bf16 MFMA)
__launch_bounds__(256)
__global__ void k_mfma_gemm(const unsigned short* __restrict__ Xb,
                            const unsigned short* __restrict__ Wt,
                            unsigned short* __restrict__ H) {
  __shared__ __align__(16) char lds[32768];
  const int tid = threadIdx.x;
  const int lane = tid & 63;
  const int wave = tid >> 6;
  const int wr = wave >> 1, wc = wave & 1;
  const int brow = blockIdx.y * 128;
  const int bcol = blockIdx.x * 128;

  f32x4 acc[4][4];
  const f32x4 zero = {0.f, 0.f, 0.f, 0.f};
#pragma unroll
  for (int m = 0; m < 4; m++)
#pragma unroll
    for (int n = 0; n < 4; n++) acc[m][n] = zero;

  int rowA[4], kcS[4], ldsOff[4];
#pragma unroll
  for (int i = 0; i < 4; i++) {
    int s = (i * 4 + wave) * 64 + lane;
    int row = s >> 3;
    int c = s & 7;
    rowA[i] = row;
    kcS[i] = (c ^ (row & 7)) * 8;
    ldsOff[i] = ((i * 4 + wave) * 64) * 16;
  }

  const int fr = lane & 15;
  const int fq = lane >> 4;
  const int arow0 = wr * 64 + fr;
  const int brow0 = wc * 64 + fr;
  const int sw = lane & 7;

  for (int t = 0; t < KPAD / 64; ++t) {
    const int k0 = t * 64;
#pragma unroll
    for (int i = 0; i < 4; i++) {
      const unsigned short* g = Xb + (size_t)(brow + rowA[i]) * KPAD + k0 + kcS[i];
      __builtin_amdgcn_global_load_lds(
          (const __attribute__((address_space(1))) void*)g,
          (__attribute__((address_space(3))) void*)(lds + ldsOff[i]), 16, 0, 0);
    }
#pragma unroll
    for (int i = 0; i < 4; i++) {
      const unsigned short* g = Wt + (size_t)(bcol + rowA[i]) * KPAD + k0 + kcS[i];
      __builtin_amdgcn_global_load_lds(
          (const __attribute__((address_space(1))) void*)g,
          (__attribute__((address_space(3))) void*)(lds + 16384 + ldsOff[i]), 16, 0, 0);
    }
    __syncthreads();

#pragma unroll
    for (int kk = 0; kk < 2; kk++) {
      const int cidx = ((kk * 4 + fq) ^ sw) * 16;
      bf16x8 av[4], bv[4];
#pragma unroll
      for (int m = 0; m < 4; m++)
        av[m] = *(const bf16x8*)(lds + (arow0 + m * 16) * 128 + cidx);
#pragma unroll
      for (int n = 0; n < 4; n++)
        bv[n] = *(const bf16x8*)(lds + 16384 + (brow0 + n * 16) * 128 + cidx);
#pragma unroll
      for (int m = 0; m < 4; m++)
#pragma unroll
        for (int n = 0; n < 4; n++)
          acc[m][n] = __builtin_amdgcn_mfma_f32_16x16x32_bf16(av[m], bv[n], acc[m][n], 0, 0, 0);
    }
    __syncthreads();
  }

#pragma unroll
  for (int m = 0; m < 4; m++) {
    const int r0 = brow + wr * 64 + m * 16 + fq * 4;
#pragma unroll
    for (int n = 0; n < 4; n++) {
      const int col = bcol + wc * 64 + n * 16 + fr;
#pragma unroll
      for (int j = 0; j < 4; j++) {
        int r = r0 + j;
        if (r < N_NODES) H[(size_t)r * HCOLS + col] = f2bf(acc[m][n][j]);
      }
    }
  }
}

// ------------------------------------------------- conv1 aggregation (pull, MLP)
// grid = (N_NODES/4, 2 branches), 256 threads = 4 waves = 4 nodes.
// Wave: lane owns 4 cols (ushort4 = 8B gather/lane, 512B/row-half).
// Edge loop unrolled x4 with int2 (src,norm) records -> 4 gathers in flight.
__global__ void k_agg(const unsigned short* __restrict__ h,
                      const float* __restrict__ dinvL, const float* __restrict__ dinvG,
                      const int* __restrict__ rowL, const int* __restrict__ rowG,
                      const int2* __restrict__ erL, const int2* __restrict__ erG,
                      const float* __restrict__ biasL, const float* __restrict__ biasG,
                      unsigned short* __restrict__ xl) {
  const int br = blockIdx.y;
  const int node = blockIdx.x * 4 + (threadIdx.x >> 6);
  const int lane = threadIdx.x & 63;
  const float* __restrict__ dinv = br ? dinvG : dinvL;
  const int* __restrict__ rp = br ? rowG : rowL;
  const int2* __restrict__ er = br ? erG : erL;
  const float* __restrict__ bias = br ? biasG : biasL;
  const int off = br ? 256 : 0;
  const size_t lcol = off + lane * 4;

  float di = dinv[node];
  float w0 = di * di;  // self-loop norm
  ushort4 u = *(const ushort4*)(h + (size_t)node * HCOLS + lcol);
  float a0 = w0 * bf2f(u.x), a1 = w0 * bf2f(u.y), a2 = w0 * bf2f(u.z), a3 = w0 * bf2f(u.w);

  int e = rp[node];
  const int e1 = rp[node + 1];
  for (; e + 4 <= e1; e += 4) {
    int2 r0 = er[e + 0], r1 = er[e + 1], r2 = er[e + 2], r3 = er[e + 3];
    ushort4 v0 = *(const ushort4*)(h + (size_t)r0.x * HCOLS + lcol);
    ushort4 v1 = *(const ushort4*)(h + (size_t)r1.x * HCOLS + lcol);
    ushort4 v2 = *(const ushort4*)(h + (size_t)r2.x * HCOLS + lcol);
    ushort4 v3 = *(const ushort4*)(h + (size_t)r3.x * HCOLS + lcol);
    float w0f = __int_as_float(r0.y), w1f = __int_as_float(r1.y);
    float w2f = __int_as_float(r2.y), w3f = __int_as_float(r3.y);
    a0 = fmaf(w0f, bf2f(v0.x), a0); a1 = fmaf(w0f, bf2f(v0.y), a1);
    a2 = fmaf(w0f, bf2f(v0.z), a2); a3 = fmaf(w0f, bf2f(v0.w), a3);
    a0 = fmaf(w1f, bf2f(v1.x), a0); a1 = fmaf(w1f, bf2f(v1.y), a1);
    a2 = fmaf(w1f, bf2f(v1.z), a2); a3 = fmaf(w1f, bf2f(v1.w), a3);
    a0 = fmaf(w2f, bf2f(v2.x), a0); a1 = fmaf(w2f, bf2f(v2.y), a1);
    a2 = fmaf(w2f, bf2f(v2.z), a2); a3 = fmaf(w2f, bf2f(v2.w), a3);
    a0 = fmaf(w3f, bf2f(v3.x), a0); a1 = fmaf(w3f, bf2f(v3.y), a1);
    a2 = fmaf(w3f, bf2f(v3.z), a2); a3 = fmaf(w3f, bf2f(v3.w), a3);
  }
  for (; e < e1; e++) {
    int2 r = er[e];
    float w = __int_as_float(r.y);
    ushort4 v = *(const ushort4*)(h + (size_t)r.x * HCOLS + lcol);
    a0 = fmaf(w, bf2f(v.x), a0);
    a1 = fmaf(w, bf2f(v.y), a1);
    a2 = fmaf(w, bf2f(v.z), a2);
    a3 = fmaf(w, bf2f(v.w), a3);
  }
  float4 b = *(const float4*)(bias + lane * 4);
  ushort4 o;
  o.x = f2bf(fmaxf(a0 + b.x, 0.f));
  o.y = f2bf(fmaxf(a1 + b.y, 0.f));
  o.z = f2bf(fmaxf(a2 + b.z, 0.f));
  o.w = f2bf(fmaxf(a3 + b.w, 0.f));
  *(ushort4*)(xl + (size_t)node * HCOLS + lcol) = o;
}

// --------------------------------- pool2: Spart[br][chunk][g][col] = c^T @ xl chunk
__launch_bounds__(256)
__global__ void k_pool2(const unsigned short* __restrict__ xl,
                        const float* __restrict__ cL, const float* __restrict__ cG,
                        float* __restrict__ Spart) {
  __shared__ float cs[64][64];  // 16 KB: 64 nodes x 64 graphs
  const int t = threadIdx.x;    // col 0..255
  const int chunk = blockIdx.x;
  const int br = blockIdx.y;
  const float* __restrict__ C = br ? cG : cL;
  const int xoff = br ? 256 : 0;
  const int n0 = chunk * PCH;
  float acc[64];
#pragma unroll
  for (int g = 0; g < 64; g++) acc[g] = 0.f;

  for (int tile = 0; tile < PCH; tile += 64) {
    const int base = n0 + tile;
    __syncthreads();
#pragma unroll
    for (int i = 0; i < 16; i++) {
      int idx = i * 256 + t;  // 0..4095
      int nn = idx >> 6, gg = idx & 63;
      int node = base + nn;
      cs[nn][gg] = (node < N_NODES) ? C[(size_t)node * 64 + gg] : 0.f;
    }
    __syncthreads();
    for (int nn = 0; nn < 64; nn++) {
      int node = base + nn;
      float v = (node < N_NODES) ? bf2f(xl[(size_t)node * HCOLS + xoff + t]) : 0.f;
#pragma unroll
      for (int g4 = 0; g4 < 16; g4++) {
        float4 cv = *(const float4*)&cs[nn][g4 * 4];
        acc[g4 * 4 + 0] = fmaf(cv.x, v, acc[g4 * 4 + 0]);
        acc[g4 * 4 + 1] = fmaf(cv.y, v, acc[g4 * 4 + 1]);
        acc[g4 * 4 + 2] = fmaf(cv.z, v, acc[g4 * 4 + 2]);
        acc[g4 * 4 + 3] = fmaf(cv.w, v, acc[g4 * 4 + 3]);
      }
    }
  }
  float* sp = Spart + ((size_t)br * NCHUNK + chunk) * 16384 + t;
#pragma unroll
  for (int g = 0; g < 64; g++) sp[g * 256] = acc[g];
}

__global__ void k_pool_reduce(const float* __restrict__ Spart, float* __restrict__ S) {
  int i = blockIdx.x * blockDim.x + threadIdx.x;  // 0..32767
  if (i >= 2 * 16384) return;
  int br = i >> 14, idx = i & 16383;
  const float* p = Spart + (size_t)br * NCHUNK * 16384 + idx;
  float s = 0.f;
  for (int ch = 0; ch < NCHUNK; ch++) s += p[(size_t)ch * 16384];
  S[i] = s;
}

// ---------------------------------------------------------------- final fuse
__global__ void k_final(const float* __restrict__ S,  // [2][64][256]
                        const float* __restrict__ Wl2, const float* __restrict__ bl2,
                        const float* __restrict__ Wg2, const float* __restrict__ bg2,
                        const float* __restrict__ Wf, const float* __restrict__ bf,
                        const int* __restrict__ cnt, float* __restrict__ out) {
  __shared__ float pl[OUT_DIM], pg[OUT_DIM];
  int g = blockIdx.x, t = threadIdx.x;
  float invc = 1.0f / fmaxf((float)cnt[g], 1.0f);
  const float* Sl = S + (size_t)g * HIDDEN;
  const float* Sg = S + (size_t)N_GRAPHS * HIDDEN + (size_t)g * HIDDEN;
  float al = 0.f, ag = 0.f;
  for (int k = 0; k < HIDDEN; k++) {
    al = fmaf(Sl[k], Wl2[k * OUT_DIM + t], al);
    ag = fmaf(Sg[k], Wg2[k * OUT_DIM + t], ag);
  }
  pl[t] = al * invc + bl2[t];
  pg[t] = ag * invc + bg2[t];
  __syncthreads();
  float o = bf[t];
  for (int j = 0; j < OUT_DIM; j++) {
    o = fmaf(pl[j], Wf[j * OUT_DIM + t], o);
    o = fmaf(pg[j], Wf[(OUT_DIM + j) * OUT_DIM + t], o);
  }
  out[(size_t)g * OUT_DIM + t] = fmaxf(o, 0.f);
}

// ---------------------------------------------------------------- launch
extern "C" void kernel_launch(void* const* d_in, const int* in_sizes, int n_in,
                              void* d_out, int out_size, void* d_ws, size_t ws_size,
                              hipStream_t stream) {
  const float* x = (const float*)d_in[0];
  const int* el = (const int*)d_in[1];
  const int* eg = (const int*)d_in[2];
  const int* batch = (const int*)d_in[3];
  const float* Wl1 = (const float*)d_in[4];
  const float* bl1 = (const float*)d_in[5];
  const float* Wl2 = (const float*)d_in[6];
  const float* bl2 = (const float*)d_in[7];
  const float* Wg1 = (const float*)d_in[8];
  const float* bg1 = (const float*)d_in[9];
  const float* Wg2 = (const float*)d_in[10];
  const float* bg2 = (const float*)d_in[11];
  const float* Wf = (const float*)d_in[12];
  const float* bf = (const float*)d_in[13];
  float* out = (float*)d_out;
  char* ws = (char*)d_ws;

  // ---- workspace layout (256B aligned). Zero-region first (single memset).
  const size_t NPAD = 200192;  // 50000*4 padded
  size_t off = 0;
  int* deg_l = (int*)(ws + off); off += NPAD;
  int* deg_g = (int*)(ws + off); off += NPAD;
  int* cur_l = (int*)(ws + off); off += NPAD;
  int* cur_g = (int*)(ws + off); off += NPAD;
  int* cnt = (int*)(ws + off); off += 256;
  float* c_l = (float*)(ws + off); off += (size_t)N_NODES * 64 * 4;  // 12.8 MB
  float* c_g = (float*)(ws + off); off += (size_t)N_NODES * 64 * 4;  // 12.8 MB
  const size_t zero_bytes = off;
  float* S = (float*)(ws + off); off += (size_t)2 * N_GRAPHS * HIDDEN * 4;
  float* dinv_l = (float*)(ws + off); off += NPAD;
  float* dinv_g = (float*)(ws + off); off += NPAD;
  int* row_l = (int*)(ws + off); off += NPAD;
  int* row_g = (int*)(ws + off); off += NPAD;
  int* incl = (int*)(ws + off); off += NPAD;
  int* bsums = (int*)(ws + off); off += 256;
  int2* er_l = (int2*)(ws + off); off += (size_t)EDGES_L * 8;   // 6.4 MB
  int2* er_g = (int2*)(ws + off); off += (size_t)EDGES_G * 8;   // 12.8 MB
  unsigned short* xb = (unsigned short*)(ws + off); off += (size_t)MPAD * KPAD * 2;  // 211 MB
  unsigned short* Wt = (unsigned short*)(ws + off); off += (size_t)HCOLS * KPAD * 2;
  unsigned short* h = (unsigned short*)(ws + off); off += (size_t)N_NODES * HCOLS * 2;   // 51.2 MB
  unsigned short* xl = (unsigned short*)(ws + off); off += (size_t)N_NODES * HCOLS * 2;  // 51.2 MB
  // Spart aliases xb: xb is dead after k_mfma_gemm, Spart written after (pool2).
  float* Spart = (float*)xb;  // 2*196*16384*4 = 25.7 MB << 211 MB

  const int* srcL = el;
  const int* dstL = el + EDGES_L;
  const int* srcG = eg;
  const int* dstG = eg + EDGES_G;

  hipMemsetAsync(ws, 0, zero_bytes, stream);

  {
    long long tot = (long long)MPAD * (KPAD / 4);
    k_cvt_x<<<(int)((tot + 255) / 256), 256, 0, stream>>>(x, xb);
    k_cvt_w<<<(HCOLS * KPAD + 255) / 256, 256, 0, stream>>>(Wl1, Wg1, Wt);
  }

  k_degree<<<(EDGES_L + 255) / 256, 256, 0, stream>>>(dstL, EDGES_L, deg_l);
  k_degree<<<(EDGES_G + 255) / 256, 256, 0, stream>>>(dstG, EDGES_G, deg_g);
  k_dinv<<<(N_NODES + 255) / 256, 256, 0, stream>>>(deg_l, deg_g, dinv_l, dinv_g);

  const int NB = (N_NODES + 1023) / 1024;  // 49
  k_scan_block<<<NB, 1024, 0, stream>>>(deg_l, N_NODES, incl, bsums);
  k_scan_tops<<<1, 64, 0, stream>>>(bsums, NB);
  k_scan_fix<<<(N_NODES + 255) / 256, 256, 0, stream>>>(incl, bsums, N_NODES, row_l);
  k_scan_block<<<NB, 1024, 0, stream>>>(deg_g, N_NODES, incl, bsums);
  k_scan_tops<<<1, 64, 0, stream>>>(bsums, NB);
  k_scan_fix<<<(N_NODES + 255) / 256, 256, 0, stream>>>(incl, bsums, N_NODES, row_g);

  k_scatter<<<(EDGES_L + 255) / 256, 256, 0, stream>>>(srcL, dstL, EDGES_L, dinv_l, row_l,
                                                       cur_l, er_l);
  k_scatter<<<(EDGES_G + 255) / 256, 256, 0, stream>>>(srcG, dstG, EDGES_G, dinv_g, row_g,
                                                       cur_g, er_g);
  k_count<<<(N_NODES + 255) / 256, 256, 0, stream>>>(batch, cnt);

  // c-matrix build (needs dinv only)
  k_cbuild<<<(EDGES_L + 255) / 256, 256, 0, stream>>>(srcL, dstL, EDGES_L, dinv_l, batch, c_l);
  k_cbuild<<<(EDGES_G + 255) / 256, 256, 0, stream>>>(srcG, dstG, EDGES_G, dinv_g, batch, c_g);
  k_cself<<<(N_NODES + 255) / 256, 256, 0, stream>>>(batch, dinv_l, dinv_g, c_l, c_g);

  // GEMM1: 4 N-tiles x 391 M-tiles
  dim3 ggrid(4, MPAD / 128);
  k_mfma_gemm<<<ggrid, 256, 0, stream>>>(xb, Wt, h);

  // conv1 aggregation: both branches, 4-deep unrolled gather
  dim3 agrid(N_NODES / 4, 2);
  k_agg<<<agrid, 256, 0, stream>>>(h, dinv_l, dinv_g, row_l, row_g, er_l, er_g, bl1, bg1, xl);

  // pool2 (reads xl + c sequentially; writes partials; aliased over dead xb)
  dim3 pgrid(NCHUNK, 2);
  k_pool2<<<pgrid, 256, 0, stream>>>(xl, c_l, c_g, Spart);
  k_pool_reduce<<<(2 * 16384 + 255) / 256, 256, 0, stream>>>(Spart, S);

  k_final<<<N_GRAPHS, OUT_DIM, 0, stream>>>(S, Wl2, bl2, Wg2, bg2, Wf, bf, cnt, out);
}